// Round 7
// baseline (87.234 us; speedup 1.0000x reference)
//
#include <hip/hip_runtime.h>
#include <cstddef>

#define BATCH 512
#define UNITS 512
#define HID   64
#define CHUNKS 2                       // batch chunks of 256 rows
#define ROWS_PER_CHUNK (BATCH / CHUNKS)

typedef __bf16 bf16x8 __attribute__((ext_vector_type(8)));
typedef float  f32x4  __attribute__((ext_vector_type(4)));

__device__ __forceinline__ float fast_sigmoid(float v) {
    return 1.0f / (1.0f + __expf(-v));
}
__device__ __forceinline__ float fast_tanh(float v) {
    return 2.0f / (1.0f + __expf(-2.0f * v)) - 1.0f;
}

// R7: column-split + fully-linear LDS.
// Block = (unit, col-half, chunk): 512 thr = 8 waves x 16 rows, 32 output
// cols, 128 rows/iter, 2 iters. LDS 24.5KB -> 6 blocks/CU by LDS; ~60 regs.
// LDS chunk layout [g][ks][n][lg][lr] (16B chunks):
//   - compute read (g,ks,n): addr = g*4096 + ks*2048 + n*1024 + lane*16
//     -> contiguous 1KB wave sweep (throughput-optimal, 2-way-free)
//   - staging write: chunk_id = p*512 + tid, addr = chunk_id*16 -> linear too
//     (we choose which (i,o) chunk each thread stages, so BOTH sides linear;
//      R6's rot swizzle caused 3.5M conflict cycles)
__global__ __launch_bounds__(512, 3)
void gru_kernel(const float* __restrict__ x,    const float* __restrict__ h,
                const float* __restrict__ W_ir, const float* __restrict__ b_ir,
                const float* __restrict__ W_hr, const float* __restrict__ b_hr,
                const float* __restrict__ W_iz, const float* __restrict__ b_iz,
                const float* __restrict__ W_hz, const float* __restrict__ b_hz,
                const float* __restrict__ W_in, const float* __restrict__ b_in,
                const float* __restrict__ W_hn, const float* __restrict__ b_hn,
                float* __restrict__ out)
{
    __shared__ __align__(16) unsigned char wlds[6 * 256 * 16]; // 24 KB
    __shared__ float blds[4][32];                              // 0.5 KB

    // blockIdx = u*4 + ck*2 + ch  (ch fastest: col-halves of same rows adjacent)
    const int ch = blockIdx.x & 1;          // column half
    const int ck = (blockIdx.x >> 1) & 1;   // batch chunk
    const int u  = blockIdx.x >> 2;         // unit

    const int tid  = threadIdx.x;
    const int lane = tid & 63;
    const int w    = tid >> 6;   // 0..7 : 16-row group within 128-row tile
    const int lr   = lane & 15;  // row (A) / col (B,D) within fragment
    const int lg   = lane >> 4;  // k-group 0..3

    const float* Wg[6] = {
        W_ir + (size_t)u * 64 * 64, W_hr + (size_t)u * 64 * 64,
        W_iz + (size_t)u * 64 * 64, W_hz + (size_t)u * 64 * 64,
        W_in + (size_t)u * 64 * 64, W_hn + (size_t)u * 64 * 64 };

    // ---- stage weights: 3 passes, linear LDS writes ----
    // chunk_id = p*512 + tid in [0,1536): g = cid>>8, c = cid&255,
    // c = ks*128 + n*64 + lg*16 + lr; chunk holds W[ks*32+lg*8+e][ch*32+n*16+lr]
    {
      #pragma unroll
      for (int p = 0; p < 3; ++p) {
        const int cid = p * 512 + tid;
        const int c   = cid & 255;
        const int ks_s = c >> 7;
        const int n_s  = (c >> 6) & 1;
        const int lg_s = (c >> 4) & 3;
        const int lr_s = c & 15;
        const int i0   = ks_s * 32 + lg_s * 8;
        const int og   = ch * 32 + n_s * 16 + lr_s;
        const float* q = ((tid & 256) ? Wg[p * 2 + 1] : Wg[p * 2])
                         + (size_t)i0 * 64 + og;
        bf16x8 f;
        #pragma unroll
        for (int e = 0; e < 8; ++e) f[e] = (__bf16)q[(size_t)e * 64];
        *(bf16x8*)(wlds + (size_t)cid * 16) = f;
      }
    }

    // ---- stage bias sums (this col-half only) ----
    if (tid < 128) {
      const int o_l = tid & 31;
      const int o   = u * 64 + ch * 32 + o_l;
      const int which = tid >> 5;
      float v;
      if      (which == 0) v = b_ir[o] + b_hr[o];
      else if (which == 1) v = b_iz[o] + b_hz[o];
      else if (which == 2) v = b_in[o];
      else                 v = b_hn[o];
      blds[which][o_l] = v;
    }

    __syncthreads();

    const f32x4 zero4 = { 0.0f, 0.0f, 0.0f, 0.0f };
    const int loff = lane * 16;

    #pragma unroll 1
    for (int it = 0; it < ROWS_PER_CHUNK / 128; ++it) {
      const int brow0 = ck * ROWS_PER_CHUNK + it * 128 + w * 16;

      // ---- A fragments: this wave's 16 rows of x,h (8 contiguous k/lane) ----
      bf16x8 ax[2], ah[2];
      {
        const int row = brow0 + lr;
        const float* px = x + ((size_t)row * UNITS + u) * HID;
        const float* ph = h + ((size_t)row * UNITS + u) * HID;
        #pragma unroll
        for (int ks = 0; ks < 2; ++ks) {
          const int i0 = ks * 32 + lg * 8;
          f32x4 xv0 = *(const f32x4*)(px + i0);
          f32x4 xv1 = *(const f32x4*)(px + i0 + 4);
          f32x4 hv0 = *(const f32x4*)(ph + i0);
          f32x4 hv1 = *(const f32x4*)(ph + i0 + 4);
          bf16x8 fx, fh;
          #pragma unroll
          for (int e = 0; e < 4; ++e) {
            fx[e]     = (__bf16)xv0[e];
            fx[4 + e] = (__bf16)xv1[e];
            fh[e]     = (__bf16)hv0[e];
            fh[4 + e] = (__bf16)hv1[e];
          }
          ax[ks] = fx;
          ah[ks] = fh;
        }
      }

      // ---- n-outer: one 16-col fragment at a time, 16 acc regs live ----
      #pragma unroll 1
      for (int n = 0; n < 2; ++n) {
        const int o = ch * 32 + n * 16 + lr;

        // epilogue h reloads issued early (L1/L2 hits; latency under MFMAs)
        float hv[4];
        #pragma unroll
        for (int j = 0; j < 4; ++j) {
          const int row = brow0 + lg * 4 + j;
          hv[j] = h[((size_t)row * UNITS + u) * HID + o];
        }
        const float br = blds[0][n * 16 + lr];
        const float bz = blds[1][n * 16 + lr];
        const float bi = blds[2][n * 16 + lr];
        const float bh = blds[3][n * 16 + lr];

        f32x4 accr = zero4, accz = zero4, acca = zero4, accb = zero4;
        #pragma unroll
        for (int ks = 0; ks < 2; ++ks) {
          const unsigned char* bp = wlds + n * 1024 + ks * 2048 + loff;
          bf16x8 b0 = *(const bf16x8*)(bp + 0 * 4096);
          bf16x8 b1 = *(const bf16x8*)(bp + 1 * 4096);
          bf16x8 b2 = *(const bf16x8*)(bp + 2 * 4096);
          bf16x8 b3 = *(const bf16x8*)(bp + 3 * 4096);
          bf16x8 b4 = *(const bf16x8*)(bp + 4 * 4096);
          bf16x8 b5 = *(const bf16x8*)(bp + 5 * 4096);
          accr = __builtin_amdgcn_mfma_f32_16x16x32_bf16(ax[ks], b0, accr, 0, 0, 0);
          accr = __builtin_amdgcn_mfma_f32_16x16x32_bf16(ah[ks], b1, accr, 0, 0, 0);
          accz = __builtin_amdgcn_mfma_f32_16x16x32_bf16(ax[ks], b2, accz, 0, 0, 0);
          accz = __builtin_amdgcn_mfma_f32_16x16x32_bf16(ah[ks], b3, accz, 0, 0, 0);
          acca = __builtin_amdgcn_mfma_f32_16x16x32_bf16(ax[ks], b4, acca, 0, 0, 0);
          accb = __builtin_amdgcn_mfma_f32_16x16x32_bf16(ah[ks], b5, accb, 0, 0, 0);
        }

        // ---- epilogue for this n ----
        // D layout (HW-verified m89): col = lane&15, row = (lane>>4)*4 + j
        #pragma unroll
        for (int j = 0; j < 4; ++j) {
          const int row = brow0 + lg * 4 + j;
          const size_t idx = ((size_t)row * UNITS + u) * HID + o;
          const float rv = fast_sigmoid(accr[j] + br);
          const float zv = fast_sigmoid(accz[j] + bz);
          const float nv = fast_tanh(acca[j] + bi + rv * (accb[j] + bh));
          out[idx] = (1.0f - zv) * nv + zv * hv[j];
        }
      }
    }
}

extern "C" void kernel_launch(void* const* d_in, const int* in_sizes, int n_in,
                              void* d_out, int out_size, void* d_ws, size_t ws_size,
                              hipStream_t stream) {
    const float* x    = (const float*)d_in[0];
    const float* h    = (const float*)d_in[1];
    const float* W_ir = (const float*)d_in[2];
    const float* b_ir = (const float*)d_in[3];
    const float* W_hr = (const float*)d_in[4];
    const float* b_hr = (const float*)d_in[5];
    const float* W_iz = (const float*)d_in[6];
    const float* b_iz = (const float*)d_in[7];
    const float* W_hz = (const float*)d_in[8];
    const float* b_hz = (const float*)d_in[9];
    const float* W_in = (const float*)d_in[10];
    const float* b_in = (const float*)d_in[11];
    const float* W_hn = (const float*)d_in[12];
    const float* b_hn = (const float*)d_in[13];
    float* out = (float*)d_out;

    gru_kernel<<<dim3(UNITS * 2 * CHUNKS), dim3(512), 0, stream>>>(
        x, h, W_ir, b_ir, W_hr, b_hr, W_iz, b_iz, W_hz, b_hz,
        W_in, b_in, W_hn, b_hn, out);
}

// Round 8
// 55.600 us; speedup vs baseline: 1.5689x; 1.5689x over previous
//
#include <hip/hip_runtime.h>
#include <cstddef>

#define BATCH 512
#define UNITS 512
#define HID   64

typedef __bf16 bf16x8 __attribute__((ext_vector_type(8)));
typedef float  f32x4  __attribute__((ext_vector_type(4)));

__device__ __forceinline__ float fast_sigmoid(float v) {
    return 1.0f / (1.0f + __expf(-v));
}
__device__ __forceinline__ float fast_tanh(float v) {
    return 2.0f / (1.0f + __expf(-2.0f * v)) - 1.0f;
}

// R8 = R6 structure + R7's linear LDS + CHUNKS=1.
// Grid = 512 blocks (1 unit each, ALL 64 cols -> x,h read exactly once;
// R7 proved col-split's doubled x/h reads are NOT L3-absorbed: +60MB HBM).
// Block: 512 thr = 8 waves x 16 rows, 128 rows/iter, 4 iters; W staged ONCE.
// LDS layout [g][ks][n][lg][lr] in 16B chunks (R7-verified conflict-free):
//   - compute read (g,ks,n): g*8192 + ks*4096 + n*1024 + lane*16
//     -> contiguous 1KB wave sweep
//   - staging write pass g: addr = g*8192 + tid*16 -> linear
//     (R6's rot swizzle cost 3.5M conflict cycles; R7's linear = 0)
// Registers: A 16 + B 24 + acc 16 + hv 4 + misc -> ~60 arch (R6-verified).
__global__ __launch_bounds__(512, 3)
void gru_kernel(const float* __restrict__ x,    const float* __restrict__ h,
                const float* __restrict__ W_ir, const float* __restrict__ b_ir,
                const float* __restrict__ W_hr, const float* __restrict__ b_hr,
                const float* __restrict__ W_iz, const float* __restrict__ b_iz,
                const float* __restrict__ W_hz, const float* __restrict__ b_hz,
                const float* __restrict__ W_in, const float* __restrict__ b_in,
                const float* __restrict__ W_hn, const float* __restrict__ b_hn,
                float* __restrict__ out)
{
    __shared__ __align__(16) unsigned char wlds[6 * 512 * 16]; // 48 KB
    __shared__ float blds[4][64];                              // 1 KB

    const int u    = blockIdx.x;
    const int tid  = threadIdx.x;
    const int lane = tid & 63;
    const int w    = tid >> 6;   // 0..7 : 16-row group within 128-row tile
    const int lr   = lane & 15;  // row (A) / col (B,D) within fragment
    const int lg   = lane >> 4;  // k-group 0..3

    const float* Wg[6] = {
        W_ir + (size_t)u * 64 * 64, W_hr + (size_t)u * 64 * 64,
        W_iz + (size_t)u * 64 * 64, W_hz + (size_t)u * 64 * 64,
        W_in + (size_t)u * 64 * 64, W_hn + (size_t)u * 64 * 64 };

    // ---- stage weights: 6 passes (one per matrix), linear LDS writes ----
    // tid -> chunk: ks = tid>>8, n = (tid>>6)&3, lg_s = (tid>>4)&3, lr_s = tid&15
    // chunk holds W[ks*32+lg_s*8+e][n*16+lr_s], e = 0..7
    {
      const int ks_s = tid >> 8;
      const int n_s  = (tid >> 6) & 3;
      const int lg_s = (tid >> 4) & 3;
      const int lr_s = tid & 15;
      const int i0   = ks_s * 32 + lg_s * 8;
      const int o_s  = n_s * 16 + lr_s;
      #pragma unroll
      for (int g = 0; g < 6; ++g) {
        const float* q = Wg[g] + (size_t)i0 * 64 + o_s;
        bf16x8 f;
        #pragma unroll
        for (int e = 0; e < 8; ++e) f[e] = (__bf16)q[(size_t)e * 64];
        *(bf16x8*)(wlds + (size_t)(g * 512 + tid) * 16) = f;
      }
    }

    // ---- stage bias sums into LDS (1KB) ----
    if (tid < 256) {
      const int o_l = tid & 63;
      const int which = tid >> 6;
      const int o = u * 64 + o_l;
      float v;
      if      (which == 0) v = b_ir[o] + b_hr[o];
      else if (which == 1) v = b_iz[o] + b_hz[o];
      else if (which == 2) v = b_in[o];
      else                 v = b_hn[o];
      blds[which][o_l] = v;
    }

    __syncthreads();

    const f32x4 zero4 = { 0.0f, 0.0f, 0.0f, 0.0f };
    const int loff = lane * 16;

    #pragma unroll 1
    for (int it = 0; it < 4; ++it) {
      const int brow0 = it * 128 + w * 16;

      // ---- A fragments: this wave's 16 rows of x,h (8 contiguous k/lane) ----
      bf16x8 ax[2], ah[2];
      {
        const int row = brow0 + lr;
        const float* px = x + ((size_t)row * UNITS + u) * HID;
        const float* ph = h + ((size_t)row * UNITS + u) * HID;
        #pragma unroll
        for (int ks = 0; ks < 2; ++ks) {
          const int i0 = ks * 32 + lg * 8;
          f32x4 xv0 = *(const f32x4*)(px + i0);
          f32x4 xv1 = *(const f32x4*)(px + i0 + 4);
          f32x4 hv0 = *(const f32x4*)(ph + i0);
          f32x4 hv1 = *(const f32x4*)(ph + i0 + 4);
          bf16x8 fx, fh;
          #pragma unroll
          for (int e = 0; e < 4; ++e) {
            fx[e]     = (__bf16)xv0[e];
            fx[4 + e] = (__bf16)xv1[e];
            fh[e]     = (__bf16)hv0[e];
            fh[4 + e] = (__bf16)hv1[e];
          }
          ax[ks] = fx;
          ah[ks] = fh;
        }
      }

      // ---- n-outer: one 16-col fragment at a time, 16 acc regs live ----
      #pragma unroll 1
      for (int n = 0; n < 4; ++n) {
        const int o = n * 16 + lr;

        // epilogue h reloads issued early (rows just touched -> L1 hits)
        float hv[4];
        #pragma unroll
        for (int j = 0; j < 4; ++j) {
          const int row = brow0 + lg * 4 + j;
          hv[j] = h[((size_t)row * UNITS + u) * HID + o];
        }
        const float br = blds[0][o];
        const float bz = blds[1][o];
        const float bi = blds[2][o];
        const float bh = blds[3][o];

        f32x4 accr = zero4, accz = zero4, acca = zero4, accb = zero4;
        #pragma unroll
        for (int ks = 0; ks < 2; ++ks) {
          const unsigned char* bp = wlds + ks * 4096 + n * 1024 + loff;
          bf16x8 b0 = *(const bf16x8*)(bp + 0 * 8192);
          bf16x8 b1 = *(const bf16x8*)(bp + 1 * 8192);
          bf16x8 b2 = *(const bf16x8*)(bp + 2 * 8192);
          bf16x8 b3 = *(const bf16x8*)(bp + 3 * 8192);
          bf16x8 b4 = *(const bf16x8*)(bp + 4 * 8192);
          bf16x8 b5 = *(const bf16x8*)(bp + 5 * 8192);
          accr = __builtin_amdgcn_mfma_f32_16x16x32_bf16(ax[ks], b0, accr, 0, 0, 0);
          accr = __builtin_amdgcn_mfma_f32_16x16x32_bf16(ah[ks], b1, accr, 0, 0, 0);
          accz = __builtin_amdgcn_mfma_f32_16x16x32_bf16(ax[ks], b2, accz, 0, 0, 0);
          accz = __builtin_amdgcn_mfma_f32_16x16x32_bf16(ah[ks], b3, accz, 0, 0, 0);
          acca = __builtin_amdgcn_mfma_f32_16x16x32_bf16(ax[ks], b4, acca, 0, 0, 0);
          accb = __builtin_amdgcn_mfma_f32_16x16x32_bf16(ah[ks], b5, accb, 0, 0, 0);
        }

        // ---- epilogue for this n ----
        // D layout (HW-verified m89): col = lane&15, row = (lane>>4)*4 + j
        #pragma unroll
        for (int j = 0; j < 4; ++j) {
          const int row = brow0 + lg * 4 + j;
          const size_t idx = ((size_t)row * UNITS + u) * HID + o;
          const float rv = fast_sigmoid(accr[j] + br);
          const float zv = fast_sigmoid(accz[j] + bz);
          const float nv = fast_tanh(acca[j] + bi + rv * (accb[j] + bh));
          out[idx] = (1.0f - zv) * nv + zv * hv[j];
        }
      }
    }
}

extern "C" void kernel_launch(void* const* d_in, const int* in_sizes, int n_in,
                              void* d_out, int out_size, void* d_ws, size_t ws_size,
                              hipStream_t stream) {
    const float* x    = (const float*)d_in[0];
    const float* h    = (const float*)d_in[1];
    const float* W_ir = (const float*)d_in[2];
    const float* b_ir = (const float*)d_in[3];
    const float* W_hr = (const float*)d_in[4];
    const float* b_hr = (const float*)d_in[5];
    const float* W_iz = (const float*)d_in[6];
    const float* b_iz = (const float*)d_in[7];
    const float* W_hz = (const float*)d_in[8];
    const float* b_hz = (const float*)d_in[9];
    const float* W_in = (const float*)d_in[10];
    const float* b_in = (const float*)d_in[11];
    const float* W_hn = (const float*)d_in[12];
    const float* b_hn = (const float*)d_in[13];
    float* out = (float*)d_out;

    gru_kernel<<<dim3(UNITS), dim3(512), 0, stream>>>(
        x, h, W_ir, b_ir, W_hr, b_hr, W_iz, b_iz, W_hz, b_hz,
        W_in, b_in, W_hn, b_hn, out);
}